// Round 11
// baseline (238.645 us; speedup 1.0000x reference)
//
#include <hip/hip_runtime.h>

#define BB 32
#define IDF 64
#define QL 16384
#define CDF 768
#define SL 18
#define SLP 20             // padded row stride for sT rows
#define CLP 21             // odd stride for ctx_l -> conflict-free b32 reads
#define ADIM 100

// ---------------- Kernel A: sT[b,i,s] = sum_c wic[i,c] * ctx[b,c,s]; out init.
// grid = 512 (b = blk>>4, g = blk&15), block = 256 (4 waves, wave = row i).
__global__ __launch_bounds__(256, 2) void kA_source(
        const float* __restrict__ ctx,      // [B, CDF, SL]
        const float* __restrict__ wic,      // [IDF, CDF]
        const float* __restrict__ fc_b,     // [ADIM]
        float* __restrict__ sT,             // ws: [B, IDF, SLP]
        float* __restrict__ out)            // [B, ADIM]
{
    __shared__ float ctx_l[CDF * CLP];     // 64512 B
    const int blk  = blockIdx.x;
    const int tid  = threadIdx.x;
    const int wave = tid >> 6;
    const int lane = tid & 63;
    const int b = blk >> 4;
    const int g = blk & 15;

    // fused out-init (harness poisons out every launch); kC atomics add onto it
    if (blk < 13) {
        const int t = blk * 256 + tid;
        if (t < BB * ADIM) out[t] = fc_b[t % ADIM];
    }

    const float* ctxb = ctx + (size_t)b * CDF * SL;
    for (int t = tid; t < CDF * SL; t += 256) {
        const int c = t / SL;
        const int s = t - c * SL;
        ctx_l[c * CLP + s] = ctxb[t];
    }
    __syncthreads();

    const int i = g * 4 + wave;
    const float* wrow = wic + (size_t)i * CDF;

    float acc[SL];
#pragma unroll
    for (int s = 0; s < SL; s++) acc[s] = 0.f;

#pragma unroll 2
    for (int k = 0; k < CDF / 64; k++) {
        const int c = k * 64 + lane;
        const float wv = wrow[c];                    // coalesced 256 B/wave
#pragma unroll
        for (int s = 0; s < SL; s++) acc[s] += wv * ctx_l[c * CLP + s];  // odd stride: 2-way max
    }
#pragma unroll
    for (int s = 0; s < SL; s++) {
        float a = acc[s];
#pragma unroll
        for (int off = 32; off; off >>= 1) a += __shfl_xor(a, off, 64);
        if (lane == 0) sT[((size_t)b * IDF + i) * SLP + s] = a;
    }
}

// ---------------- Kernel B: scores -> softmax -> dot(v) -> wq.
// grid = (32 qt, 32 b), block 256, 2 q/thread (float2), 4-deep rolling prefetch.
// st[i][s] read DIRECT from global with wave-uniform address -> compiler emits
// s_load into SGPRs (scalar cache path, 5 KB L2-hot) -> v_fmac v,s,v.
// NO LDS in the main loop (only the one-time v_l[18]).
__global__ __launch_bounds__(256, 2) void kB_attn(
        const float* __restrict__ inp,     // [B, IDF, QL]
        const float* __restrict__ sT,      // ws: [B, IDF, SLP]
        const float* __restrict__ conv_w,  // [IDF]
        const float* __restrict__ conv_b,  // [1]
        float* __restrict__ wq)            // ws: [B, QL]
{
    __shared__ float v_l[SL];
    const int b   = blockIdx.y;
    const int qt  = blockIdx.x;
    const int tid = threadIdx.x;
    const float* st = sT + (size_t)b * IDF * SLP;

    if (tid < SL) {                         // one-time: v[s] = sum_i cw[i]*st[i][s]
        float a = 0.f;
        for (int i = 0; i < IDF; i++) a += conv_w[i] * st[i * SLP + tid];
        v_l[tid] = a;
    }
    __syncthreads();

    const float2* ip2 = (const float2*)(inp + (size_t)b * IDF * QL + (size_t)qt * 512);

    float2 sc[SL];
#pragma unroll
    for (int s = 0; s < SL; s++) sc[s] = make_float2(0.f, 0.f);

    float2 xb[4];
#pragma unroll
    for (int j = 0; j < 4; j++) xb[j] = ip2[(size_t)j * (QL / 2) + tid];

#pragma unroll 4
    for (int i = 0; i < IDF; i++) {
        const float2 x = xb[i & 3];
        if (i + 4 < IDF) xb[i & 3] = ip2[(size_t)(i + 4) * (QL / 2) + tid];
        const float* strow = st + i * SLP;  // uniform address -> s_load
#pragma unroll
        for (int s = 0; s < SL; s++) {
            const float rs = strow[s];
            sc[s].x += x.x * rs;
            sc[s].y += x.y * rs;
        }
    }

    float2 m = sc[0];
#pragma unroll
    for (int s = 1; s < SL; s++) {
        m.x = fmaxf(m.x, sc[s].x);
        m.y = fmaxf(m.y, sc[s].y);
    }
    float2 l = make_float2(0.f, 0.f);
    float2 o = make_float2(0.f, 0.f);
#pragma unroll
    for (int s = 0; s < SL; s++) {
        const float vs = v_l[s];
        float2 p;
        p.x = __expf(sc[s].x - m.x);
        p.y = __expf(sc[s].y - m.y);
        l.x += p.x; l.y += p.y;
        o.x += p.x * vs; o.y += p.y * vs;
    }
    const float cb = conv_b[0];
    float2 res;
    res.x = o.x / l.x + cb;
    res.y = o.y / l.y + cb;
    ((float2*)(wq + (size_t)b * QL + (size_t)qt * 512))[tid] = res;
}

// ---------------- Kernel C: out[b,a] += sum_q wq[b,q] * fcw[a,q]
// grid = 320 = 4 bg(8 b) x 10 ag(10 a) x 8 qc(2048 q); block = 320 (5 waves).
__global__ __launch_bounds__(320, 2) void kC_fc(
        const float* __restrict__ wq,      // [B, QL]
        const float* __restrict__ fcw,     // [ADIM, QL]
        float* __restrict__ out)           // [B, ADIM]
{
    const int blk = blockIdx.x;
    const int bg  = blk / 80;              // 0..3
    const int rem = blk - bg * 80;
    const int ag  = rem >> 3;              // 0..9
    const int qc  = rem & 7;               // 0..7
    const int wave = threadIdx.x >> 6;     // 0..4
    const int lane = threadIdx.x & 63;
    const int a0 = ag * 10 + wave * 2;
    const int b0 = bg * 8;
    const int q0 = qc * 2048;

    float acc[2][8];
#pragma unroll
    for (int j = 0; j < 2; j++)
#pragma unroll
        for (int i = 0; i < 8; i++) acc[j][i] = 0.f;

#pragma unroll 2
    for (int k = 0; k < 8; k++) {
        const int qi = q0 + (k * 64 + lane) * 4;
        float4 fv[2];
#pragma unroll
        for (int j = 0; j < 2; j++) fv[j] = *(const float4*)(fcw + (size_t)(a0 + j) * QL + qi);
        float4 wv[8];
#pragma unroll
        for (int i = 0; i < 8; i++) wv[i] = *(const float4*)(wq + (size_t)(b0 + i) * QL + qi);
#pragma unroll
        for (int j = 0; j < 2; j++)
#pragma unroll
            for (int i = 0; i < 8; i++)
                acc[j][i] += fv[j].x * wv[i].x + fv[j].y * wv[i].y
                           + fv[j].z * wv[i].z + fv[j].w * wv[i].w;
    }

#pragma unroll
    for (int j = 0; j < 2; j++) {
#pragma unroll
        for (int i = 0; i < 8; i++) {
            float r = acc[j][i];
#pragma unroll
            for (int off = 32; off; off >>= 1) r += __shfl_xor(r, off, 64);
            if (lane == 0) atomicAdd(&out[(b0 + i) * ADIM + a0 + j], r);
        }
    }
}

extern "C" void kernel_launch(void* const* d_in, const int* in_sizes, int n_in,
                              void* d_out, int out_size, void* d_ws, size_t ws_size,
                              hipStream_t stream)
{
    const float* inputs     = (const float*)d_in[0];  // [32,64,128,128]
    const float* context    = (const float*)d_in[1];  // [32,768,18]
    const float* conv_ctx_w = (const float*)d_in[2];  // [64,768]
    const float* conv_w     = (const float*)d_in[3];  // [64]
    const float* conv_b     = (const float*)d_in[4];  // [1]
    const float* fc_w       = (const float*)d_in[5];  // [100,16384]
    const float* fc_b       = (const float*)d_in[6];  // [100]
    float* out = (float*)d_out;

    float* ws = (float*)d_ws;
    float* sT = ws;                                   // 32*64*20 = 40960 floats
    float* wq = ws + (size_t)BB * IDF * SLP;          // 524288 floats

    kA_source<<<dim3(512), dim3(256), 0, stream>>>(context, conv_ctx_w, fc_b, sT, out);
    kB_attn<<<dim3(32, BB), dim3(256), 0, stream>>>(inputs, sT, conv_w, conv_b, wq);
    kC_fc<<<dim3(320), dim3(320), 0, stream>>>(wq, fc_w, out);
}

// Round 12
// 234.799 us; speedup vs baseline: 1.0164x; 1.0164x over previous
//
#include <hip/hip_runtime.h>

#define BB 32
#define IDF 64
#define QL 16384
#define CDF 768
#define SL 18
#define SLP 20             // padded row stride for sT rows
#define CLP 21             // odd stride for ctx_l -> conflict-free b32 reads
#define ADIM 100

typedef __attribute__((address_space(3))) unsigned int lds_u32_t;
typedef __attribute__((address_space(1))) const unsigned int glb_u32_t;

// ---------------- Kernel A: sT[b,i,s] = sum_c wic[i,c] * ctx[b,c,s]; out init.
// grid = 512 (b = blk>>4, g = blk&15), block = 256 (4 waves, wave = row i).
__global__ __launch_bounds__(256, 2) void kA_source(
        const float* __restrict__ ctx,      // [B, CDF, SL]
        const float* __restrict__ wic,      // [IDF, CDF]
        const float* __restrict__ fc_b,     // [ADIM]
        float* __restrict__ sT,             // ws: [B, IDF, SLP]
        float* __restrict__ out)            // [B, ADIM]
{
    __shared__ float ctx_l[CDF * CLP];     // 64512 B
    const int blk  = blockIdx.x;
    const int tid  = threadIdx.x;
    const int wave = tid >> 6;
    const int lane = tid & 63;
    const int b = blk >> 4;
    const int g = blk & 15;

    // fused out-init (harness poisons out every launch); kC atomics add onto it
    if (blk < 13) {
        const int t = blk * 256 + tid;
        if (t < BB * ADIM) out[t] = fc_b[t % ADIM];
    }

    const float* ctxb = ctx + (size_t)b * CDF * SL;
    for (int t = tid; t < CDF * SL; t += 256) {
        const int c = t / SL;
        const int s = t - c * SL;
        ctx_l[c * CLP + s] = ctxb[t];
    }
    __syncthreads();

    const int i = g * 4 + wave;
    const float* wrow = wic + (size_t)i * CDF;

    float acc[SL];
#pragma unroll
    for (int s = 0; s < SL; s++) acc[s] = 0.f;

#pragma unroll 2
    for (int k = 0; k < CDF / 64; k++) {
        const int c = k * 64 + lane;
        const float wv = wrow[c];                    // coalesced 256 B/wave
#pragma unroll
        for (int s = 0; s < SL; s++) acc[s] += wv * ctx_l[c * CLP + s];  // odd stride: 2-way max
    }
#pragma unroll
    for (int s = 0; s < SL; s++) {
        float a = acc[s];
#pragma unroll
        for (int off = 32; off; off >>= 1) a += __shfl_xor(a, off, 64);
        if (lane == 0) sT[((size_t)b * IDF + i) * SLP + s] = a;
    }
}

// ---------------- Kernel B: scores -> softmax -> dot(v) -> wq.
// grid = (32 qt, 32 b), block 256. NEW: input streamed via global_load_lds
// (async DMA to LDS, dwordx4) into double-buffered 8-row x 512-q tiles.
// Compute: x from LDS (2 conflict-free b32/thread/i), st from uniform/scalar
// path, 36 FMAs/i. One barrier per 8-row stage (m97 2-barrier structure).
__global__ __launch_bounds__(256, 4) void kB_attn(
        const float* __restrict__ inp,     // [B, IDF, QL]
        const float* __restrict__ sT,      // ws: [B, IDF, SLP]
        const float* __restrict__ conv_w,  // [IDF]
        const float* __restrict__ conv_b,  // [1]
        float* __restrict__ wq)            // ws: [B, QL]
{
    __shared__ __align__(16) float xbuf[2][8][512];   // 2 x 16 KB, q-contiguous (NO padding: DMA layout)
    __shared__ float v_l[SL];
    const int b   = blockIdx.y;
    const int qt  = blockIdx.x;
    const int tid = threadIdx.x;
    const int wave = tid >> 6;
    const int lane = tid & 63;
    const float* st = sT + (size_t)b * IDF * SLP;

    if (tid < SL) {                         // one-time: v[s] = sum_i cw[i]*st[i][s]
        float a = 0.f;
        for (int i = 0; i < IDF; i++) a += conv_w[i] * st[i * SLP + tid];
        v_l[tid] = a;
    }

    const float* gbase = inp + (size_t)b * IDF * QL + (size_t)qt * 512;

    // stage 8 rows (16 KB) into xbuf[buf]: 16 chunks of 1 KB; wave w takes 4.
    // chunk j: row r = j>>1, half h = j&1; lane writes lds base + lane*16.
#define STAGE(st_idx, buf)                                                              \
    {                                                                                   \
        const int i0_ = (st_idx) * 8;                                                   \
        _Pragma("unroll")                                                               \
        for (int c_ = 0; c_ < 4; c_++) {                                                \
            const int j_ = wave * 4 + c_;                                               \
            const int r_ = j_ >> 1, h_ = j_ & 1;                                        \
            const float* g_ = gbase + (size_t)(i0_ + r_) * QL + h_ * 256 + lane * 4;    \
            float* l_ = &xbuf[(buf)][r_][h_ * 256];                                     \
            __builtin_amdgcn_global_load_lds((glb_u32_t*)g_, (lds_u32_t*)l_, 16, 0, 0); \
        }                                                                               \
    }

    STAGE(0, 0);

    float2 sc[SL];
#pragma unroll
    for (int s = 0; s < SL; s++) sc[s] = make_float2(0.f, 0.f);

#pragma unroll 1
    for (int k = 0; k < 8; k++) {
        __syncthreads();                  // drains vmcnt -> xbuf[k&1] ready; guards reuse
        if (k < 7) STAGE(k + 1, (k + 1) & 1);
        const int kb = k & 1;
#pragma unroll
        for (int r = 0; r < 8; r++) {
            const int i = k * 8 + r;
            const float x0 = xbuf[kb][r][tid];          // stride-1 across lanes: 2-way, free
            const float x1 = xbuf[kb][r][tid + 256];
            const float* strow = st + i * SLP;          // uniform -> scalar path
#pragma unroll
            for (int s = 0; s < SL; s++) {
                const float rs = strow[s];
                sc[s].x += x0 * rs;
                sc[s].y += x1 * rs;
            }
        }
    }

    float2 m = sc[0];
#pragma unroll
    for (int s = 1; s < SL; s++) {
        m.x = fmaxf(m.x, sc[s].x);
        m.y = fmaxf(m.y, sc[s].y);
    }
    float2 l = make_float2(0.f, 0.f);
    float2 o = make_float2(0.f, 0.f);
#pragma unroll
    for (int s = 0; s < SL; s++) {
        const float vs = v_l[s];
        float2 p;
        p.x = __expf(sc[s].x - m.x);
        p.y = __expf(sc[s].y - m.y);
        l.x += p.x; l.y += p.y;
        o.x += p.x * vs; o.y += p.y * vs;
    }
    const float cb = conv_b[0];
    float* wqb = wq + (size_t)b * QL + (size_t)qt * 512;
    wqb[tid]       = o.x / l.x + cb;
    wqb[tid + 256] = o.y / l.y + cb;
}

// ---------------- Kernel C: out[b,a] += sum_q wq[b,q] * fcw[a,q]
// grid = 320 = 4 bg(8 b) x 10 ag(10 a) x 8 qc(2048 q); block = 320 (5 waves).
__global__ __launch_bounds__(320, 2) void kC_fc(
        const float* __restrict__ wq,      // [B, QL]
        const float* __restrict__ fcw,     // [ADIM, QL]
        float* __restrict__ out)           // [B, ADIM]
{
    const int blk = blockIdx.x;
    const int bg  = blk / 80;              // 0..3
    const int rem = blk - bg * 80;
    const int ag  = rem >> 3;              // 0..9
    const int qc  = rem & 7;               // 0..7
    const int wave = threadIdx.x >> 6;     // 0..4
    const int lane = threadIdx.x & 63;
    const int a0 = ag * 10 + wave * 2;
    const int b0 = bg * 8;
    const int q0 = qc * 2048;

    float acc[2][8];
#pragma unroll
    for (int j = 0; j < 2; j++)
#pragma unroll
        for (int i = 0; i < 8; i++) acc[j][i] = 0.f;

#pragma unroll 2
    for (int k = 0; k < 8; k++) {
        const int qi = q0 + (k * 64 + lane) * 4;
        float4 fv[2];
#pragma unroll
        for (int j = 0; j < 2; j++) fv[j] = *(const float4*)(fcw + (size_t)(a0 + j) * QL + qi);
        float4 wv[8];
#pragma unroll
        for (int i = 0; i < 8; i++) wv[i] = *(const float4*)(wq + (size_t)(b0 + i) * QL + qi);
#pragma unroll
        for (int j = 0; j < 2; j++)
#pragma unroll
            for (int i = 0; i < 8; i++)
                acc[j][i] += fv[j].x * wv[i].x + fv[j].y * wv[i].y
                           + fv[j].z * wv[i].z + fv[j].w * wv[i].w;
    }

#pragma unroll
    for (int j = 0; j < 2; j++) {
#pragma unroll
        for (int i = 0; i < 8; i++) {
            float r = acc[j][i];
#pragma unroll
            for (int off = 32; off; off >>= 1) r += __shfl_xor(r, off, 64);
            if (lane == 0) atomicAdd(&out[(b0 + i) * ADIM + a0 + j], r);
        }
    }
}

extern "C" void kernel_launch(void* const* d_in, const int* in_sizes, int n_in,
                              void* d_out, int out_size, void* d_ws, size_t ws_size,
                              hipStream_t stream)
{
    const float* inputs     = (const float*)d_in[0];  // [32,64,128,128]
    const float* context    = (const float*)d_in[1];  // [32,768,18]
    const float* conv_ctx_w = (const float*)d_in[2];  // [64,768]
    const float* conv_w     = (const float*)d_in[3];  // [64]
    const float* conv_b     = (const float*)d_in[4];  // [1]
    const float* fc_w       = (const float*)d_in[5];  // [100,16384]
    const float* fc_b       = (const float*)d_in[6];  // [100]
    float* out = (float*)d_out;

    float* ws = (float*)d_ws;
    float* sT = ws;                                   // 32*64*20 = 40960 floats
    float* wq = ws + (size_t)BB * IDF * SLP;          // 524288 floats

    kA_source<<<dim3(512), dim3(256), 0, stream>>>(context, conv_ctx_w, fc_b, sT, out);
    kB_attn<<<dim3(32, BB), dim3(256), 0, stream>>>(inputs, sT, conv_w, conv_b, wq);
    kC_fc<<<dim3(320), dim3(320), 0, stream>>>(wq, fc_w, out);
}